// Round 10
// baseline (45.252 us; speedup 1.0000x reference)
//
#include <hip/hip_runtime.h>
#include <math.h>

#define NF 32
#define NE 64
#define NA 64
#define NP 496
#define W1T_S 72   // padded stride (f16) of W1t: 144B, 16B-aligned

typedef __attribute__((ext_vector_type(8))) _Float16 f16x8;
typedef __attribute__((ext_vector_type(4))) _Float16 f16x4;
typedef __attribute__((ext_vector_type(4))) float    f32x4;

// Block = 256 thr = 4 waves = 4 samples (wave-per-sample). ONE barrier (W1t).
// Phase 1+2+3 fused: per tile, logit -> w=exp(logit) -> oacc += w*inner (in-reg).
__global__ __launch_bounds__(256, 2) void afm_fwd(
    const float* __restrict__ x,    // (B,32,64)
    const float* __restrict__ W1,   // (64,64)
    const float* __restrict__ b1,   // (64)
    const float* __restrict__ w2,   // (64,1)
    const float* __restrict__ b2,   // (1)
    float* __restrict__ out,        // (B,64)
    float* __restrict__ attn,       // (B,496)
    int B)
{
    const int tid   = threadIdx.x;
    const int lane  = tid & 63;
    const int wv    = tid >> 6;     // wave = sample slot
    const int nlane = lane & 15;
    const int g     = lane >> 4;

    __shared__ __align__(16) _Float16 W1t[64][W1T_S];   // 9216 B (block-shared)
    __shared__ __align__(16) _Float16 xh[4][8][NF][8];  // 16384 B (per-wave)
    __shared__ float s_w[4][NP];                        // 7936 B raw exp weights
    // total 33536 B -> grid-limited 2 blocks/CU anyway

    // ---- block-cooperative: W1 -> W1t (f16, transposed) ----
    {
        const int e = tid & 63, a0 = (tid >> 6) << 4;
        const float* wr = W1 + e * NA + a0;
        #pragma unroll
        for (int i = 0; i < 4; ++i) {
            const float4 v = *(const float4*)(wr + 4 * i);
            W1t[a0 + 4*i + 0][e] = (_Float16)v.x;
            W1t[a0 + 4*i + 1][e] = (_Float16)v.y;
            W1t[a0 + 4*i + 2][e] = (_Float16)v.z;
            W1t[a0 + 4*i + 3][e] = (_Float16)v.w;
        }
    }

    int b = blockIdx.x * 4 + wv;
    if (b >= B) b = B - 1;          // benign dup-compute guard

    // ---- wave-local: stage x[b] -> xh (e-subtiled f16) ----
    const float* __restrict__ xb = x + (size_t)b * (NF * NE);
    {
        const int r = lane >> 1, eh = (lane & 1) << 5;   // 32 floats/lane
        #pragma unroll
        for (int i = 0; i < 8; ++i) {
            const int e0 = eh + 4 * i;
            const float4 v = *(const float4*)(xb + r * NE + e0);
            f16x4 hv = { (_Float16)v.x, (_Float16)v.y, (_Float16)v.z, (_Float16)v.w };
            *(f16x4*)&xh[wv][e0 >> 3][r][e0 & 7] = hv;   // same-wave use: lgkmcnt orders
        }
    }
    __syncthreads();   // the only barrier: W1t ready

    // ---- W1 A-frags from LDS (8 x ds_read_b128, hoisted once) ----
    f16x8 w1f[2][4];
    #pragma unroll
    for (int s = 0; s < 2; ++s)
        #pragma unroll
        for (int mt = 0; mt < 4; ++mt)
            w1f[s][mt] = *(const f16x8*)&W1t[mt * 16 + nlane][s * 32 + g * 8];

    f32x4 b1q[4], w2q[4];
    #pragma unroll
    for (int mt = 0; mt < 4; ++mt) {
        b1q[mt] = *(const f32x4*)(b1 + mt * 16 + g * 4);   // a = 16mt+4g+reg
        w2q[mt] = *(const f32x4*)(w2 + mt * 16 + g * 4);
    }
    const float bias2 = b2[0];

    // ---- per-lane (r,c) walk over striped pairs p = 31*nlane + t ----
    int pr, pc;
    {
        const int p0 = 31 * nlane;
        const float sq = sqrtf((float)(3969 - 8 * p0));
        int r = (int)((63.0f - sq) * 0.5f);
        int st = (r * (63 - r)) >> 1;
        if (p0 < st) { --r; st = (r * (63 - r)) >> 1; }
        else { const int st2 = ((r + 1) * (62 - r)) >> 1; if (p0 >= st2) { ++r; st = st2; } }
        pr = r; pc = p0 - st + r + 1;
    }

    float oacc0[8] = {0,0,0,0,0,0,0,0};   // e = 8g + j
    float oacc1[8] = {0,0,0,0,0,0,0,0};   // e = 32 + 8g + j
    float sw = 0.0f;

    #pragma unroll 4
    for (int t = 0; t < 31; ++t) {
        const f16x8 xr0 = *(const f16x8*)&xh[wv][g][pr][0];
        const f16x8 xc0 = *(const f16x8*)&xh[wv][g][pc][0];
        const f16x8 xr1 = *(const f16x8*)&xh[wv][4 + g][pr][0];
        const f16x8 xc1 = *(const f16x8*)&xh[wv][4 + g][pc][0];
        const f16x8 af0 = xr0 * xc0;                     // inner[p, e-slice]
        const f16x8 af1 = xr1 * xc1;

        f32x4 acc[4];
        #pragma unroll
        for (int mt = 0; mt < 4; ++mt) acc[mt] = b1q[mt];
        __builtin_amdgcn_s_setprio(1);
        #pragma unroll
        for (int mt = 0; mt < 4; ++mt)
            acc[mt] = __builtin_amdgcn_mfma_f32_16x16x32_f16(w1f[0][mt], af0, acc[mt], 0, 0, 0);
        #pragma unroll
        for (int mt = 0; mt < 4; ++mt)
            acc[mt] = __builtin_amdgcn_mfma_f32_16x16x32_f16(w1f[1][mt], af1, acc[mt], 0, 0, 0);
        __builtin_amdgcn_s_setprio(0);

        float pl0 = 0.f, pl1 = 0.f, pl2 = 0.f, pl3 = 0.f;
        #pragma unroll
        for (int mt = 0; mt < 4; ++mt) {
            pl0 = fmaf(fmaxf(acc[mt][0], 0.f), w2q[mt][0], pl0);
            pl1 = fmaf(fmaxf(acc[mt][1], 0.f), w2q[mt][1], pl1);
            pl2 = fmaf(fmaxf(acc[mt][2], 0.f), w2q[mt][2], pl2);
            pl3 = fmaf(fmaxf(acc[mt][3], 0.f), w2q[mt][3], pl3);
        }
        float logit = (pl0 + pl1) + (pl2 + pl3);
        logit += __shfl_xor(logit, 16);
        logit += __shfl_xor(logit, 32);                  // all lanes: pair nlane's logit

        // raw exp (R4-verified safe: fp32, logits O(+-10)); normalize at the end
        const float w = __expf(logit + bias2);
        if (lane < 16) s_w[wv][31 * lane + t] = w;       // 16 distinct banks
        sw += w;
        #pragma unroll
        for (int j = 0; j < 8; ++j) {
            oacc0[j] = fmaf(w, (float)af0[j], oacc0[j]);
            oacc1[j] = fmaf(w, (float)af1[j], oacc1[j]);
        }

        // advance (r,c) -> next pair (branchless, R8-verified)
        ++pc;
        const int wrap = (pc >= 32) ? 1 : 0;
        pr += wrap;
        pc = wrap ? (pr + 1) : pc;
    }

    // ---- cross-nlane reduce (pairs partitioned by nlane) ----
    #pragma unroll
    for (int off = 1; off < 16; off <<= 1) {
        sw += __shfl_xor(sw, off);
        #pragma unroll
        for (int j = 0; j < 8; ++j) {
            oacc0[j] += __shfl_xor(oacc0[j], off);
            oacc1[j] += __shfl_xor(oacc1[j], off);
        }
    }
    const float inv = 1.0f / sw;

    if (nlane == 0) {                                    // lanes g*16: e-slice g
        float* __restrict__ ob = out + (size_t)b * NE;
        f32x4 q;
        q = (f32x4){oacc0[0]*inv, oacc0[1]*inv, oacc0[2]*inv, oacc0[3]*inv};
        *(f32x4*)&ob[8*g + 0] = q;
        q = (f32x4){oacc0[4]*inv, oacc0[5]*inv, oacc0[6]*inv, oacc0[7]*inv};
        *(f32x4*)&ob[8*g + 4] = q;
        q = (f32x4){oacc1[0]*inv, oacc1[1]*inv, oacc1[2]*inv, oacc1[3]*inv};
        *(f32x4*)&ob[32 + 8*g + 0] = q;
        q = (f32x4){oacc1[4]*inv, oacc1[5]*inv, oacc1[6]*inv, oacc1[7]*inv};
        *(f32x4*)&ob[32 + 8*g + 4] = q;
    }

    // ---- attn = raw w * inv (same-wave LDS read-back, coalesced stores) ----
    float* __restrict__ attn_b = attn + (size_t)b * NP;
    #pragma unroll
    for (int k = 0; k < 8; ++k) {
        const int p = (k << 6) + lane;
        if (p < NP) attn_b[p] = s_w[wv][p] * inv;
    }
}

extern "C" void kernel_launch(void* const* d_in, const int* in_sizes, int n_in,
                              void* d_out, int out_size, void* d_ws, size_t ws_size,
                              hipStream_t stream) {
    const float* x  = (const float*)d_in[0];
    const float* W1 = (const float*)d_in[1];
    const float* b1 = (const float*)d_in[2];
    const float* w2 = (const float*)d_in[3];
    const float* b2 = (const float*)d_in[4];

    const int B = in_sizes[0] / (NF * NE);             // 2048
    float* out_p  = (float*)d_out;                     // (B,1,64) flat
    float* attn_p = (float*)d_out + (size_t)B * NE;    // (B,496,1) flat

    afm_fwd<<<(B + 3) / 4, 256, 0, stream>>>(x, W1, b1, w2, b2, out_p, attn_p, B);
}

// Round 11
// 27.205 us; speedup vs baseline: 1.6634x; 1.6634x over previous
//
#include <hip/hip_runtime.h>
#include <math.h>

#define NF 32
#define NE 64
#define NA 64
#define NP 496
#define W1T_S 72   // padded stride (f16) of W1t: 144B, 16B-aligned

typedef __attribute__((ext_vector_type(8))) _Float16 f16x8;
typedef __attribute__((ext_vector_type(4))) _Float16 f16x4;
typedef __attribute__((ext_vector_type(4))) float    f32x4;

// Block = 256 thr = 4 waves = 4 samples (wave-per-sample). ONE barrier (W1t).
// Fused: per tile, logit -> w=exp(logit) -> oacc += w*inner, all in registers.
// launch_bounds(256,1): VGPR cap 512 -- R9's (256,2) pinned 128 VGPR and spilled
// (FETCH 46MB / WRITE 79MB scratch amplification); occupancy is grid-limited
// at 2 blocks/CU regardless, so the relaxed cap costs nothing.
__global__ __launch_bounds__(256, 1) void afm_fwd(
    const float* __restrict__ x,    // (B,32,64)
    const float* __restrict__ W1,   // (64,64)
    const float* __restrict__ b1,   // (64)
    const float* __restrict__ w2,   // (64,1)
    const float* __restrict__ b2,   // (1)
    float* __restrict__ out,        // (B,64)
    float* __restrict__ attn,       // (B,496)
    int B)
{
    const int tid   = threadIdx.x;
    const int lane  = tid & 63;
    const int wv    = tid >> 6;     // wave = sample slot
    const int nlane = lane & 15;
    const int g     = lane >> 4;

    __shared__ __align__(16) _Float16 W1t[64][W1T_S];   // 9216 B (block-shared)
    __shared__ __align__(16) _Float16 xh[4][8][NF][8];  // 16384 B (per-wave)
    __shared__ float s_w[4][NP];                        // 7936 B raw exp weights
    // total 33536 B; grid-limited 2 blocks/CU

    // ---- block-cooperative: W1 -> W1t (f16, transposed) ----
    {
        const int e = tid & 63, a0 = (tid >> 6) << 4;
        const float* wr = W1 + e * NA + a0;
        #pragma unroll
        for (int i = 0; i < 4; ++i) {
            const float4 v = *(const float4*)(wr + 4 * i);
            W1t[a0 + 4*i + 0][e] = (_Float16)v.x;
            W1t[a0 + 4*i + 1][e] = (_Float16)v.y;
            W1t[a0 + 4*i + 2][e] = (_Float16)v.z;
            W1t[a0 + 4*i + 3][e] = (_Float16)v.w;
        }
    }

    int b = blockIdx.x * 4 + wv;
    if (b >= B) b = B - 1;          // benign dup-compute guard

    // ---- wave-local: stage x[b] -> xh (e-subtiled f16) ----
    const float* __restrict__ xb = x + (size_t)b * (NF * NE);
    {
        const int r = lane >> 1, eh = (lane & 1) << 5;   // 32 floats/lane
        #pragma unroll
        for (int i = 0; i < 8; ++i) {
            const int e0 = eh + 4 * i;
            const float4 v = *(const float4*)(xb + r * NE + e0);
            f16x4 hv = { (_Float16)v.x, (_Float16)v.y, (_Float16)v.z, (_Float16)v.w };
            *(f16x4*)&xh[wv][e0 >> 3][r][e0 & 7] = hv;   // same-wave use: lgkmcnt orders
        }
    }
    __syncthreads();   // the only barrier: W1t ready

    // ---- W1 A-frags from LDS (8 x ds_read_b128, hoisted once) ----
    f16x8 w1f[2][4];
    #pragma unroll
    for (int s = 0; s < 2; ++s)
        #pragma unroll
        for (int mt = 0; mt < 4; ++mt)
            w1f[s][mt] = *(const f16x8*)&W1t[mt * 16 + nlane][s * 32 + g * 8];

    f32x4 b1q[4], w2q[4];
    #pragma unroll
    for (int mt = 0; mt < 4; ++mt) {
        b1q[mt] = *(const f32x4*)(b1 + mt * 16 + g * 4);   // a = 16mt+4g+reg
        w2q[mt] = *(const f32x4*)(w2 + mt * 16 + g * 4);
    }
    const float bias2 = b2[0];

    // ---- per-lane (r,c) walk over striped pairs p = 31*nlane + t ----
    int pr, pc;
    {
        const int p0 = 31 * nlane;
        const float sq = sqrtf((float)(3969 - 8 * p0));
        int r = (int)((63.0f - sq) * 0.5f);
        int st = (r * (63 - r)) >> 1;
        if (p0 < st) { --r; st = (r * (63 - r)) >> 1; }
        else { const int st2 = ((r + 1) * (62 - r)) >> 1; if (p0 >= st2) { ++r; st = st2; } }
        pr = r; pc = p0 - st + r + 1;
    }

    float oacc0[8] = {0,0,0,0,0,0,0,0};   // e = 8g + j
    float oacc1[8] = {0,0,0,0,0,0,0,0};   // e = 32 + 8g + j
    float sw = 0.0f;

    for (int t = 0; t < 31; ++t) {
        const f16x8 xr0 = *(const f16x8*)&xh[wv][g][pr][0];
        const f16x8 xc0 = *(const f16x8*)&xh[wv][g][pc][0];
        const f16x8 xr1 = *(const f16x8*)&xh[wv][4 + g][pr][0];
        const f16x8 xc1 = *(const f16x8*)&xh[wv][4 + g][pc][0];
        const f16x8 af0 = xr0 * xc0;                     // inner[p, e-slice]
        const f16x8 af1 = xr1 * xc1;

        f32x4 acc[4];
        #pragma unroll
        for (int mt = 0; mt < 4; ++mt) acc[mt] = b1q[mt];
        __builtin_amdgcn_s_setprio(1);
        #pragma unroll
        for (int mt = 0; mt < 4; ++mt)
            acc[mt] = __builtin_amdgcn_mfma_f32_16x16x32_f16(w1f[0][mt], af0, acc[mt], 0, 0, 0);
        #pragma unroll
        for (int mt = 0; mt < 4; ++mt)
            acc[mt] = __builtin_amdgcn_mfma_f32_16x16x32_f16(w1f[1][mt], af1, acc[mt], 0, 0, 0);
        __builtin_amdgcn_s_setprio(0);

        float pl0 = 0.f, pl1 = 0.f, pl2 = 0.f, pl3 = 0.f;
        #pragma unroll
        for (int mt = 0; mt < 4; ++mt) {
            pl0 = fmaf(fmaxf(acc[mt][0], 0.f), w2q[mt][0], pl0);
            pl1 = fmaf(fmaxf(acc[mt][1], 0.f), w2q[mt][1], pl1);
            pl2 = fmaf(fmaxf(acc[mt][2], 0.f), w2q[mt][2], pl2);
            pl3 = fmaf(fmaxf(acc[mt][3], 0.f), w2q[mt][3], pl3);
        }
        float logit = (pl0 + pl1) + (pl2 + pl3);
        logit += __shfl_xor(logit, 16);
        logit += __shfl_xor(logit, 32);                  // all lanes: pair nlane's logit

        // raw exp (R4-verified safe: fp32, logits O(+-10)); normalize at the end
        const float w = __expf(logit + bias2);
        if (lane < 16) s_w[wv][31 * lane + t] = w;       // 16 distinct banks
        sw += w;
        #pragma unroll
        for (int j = 0; j < 8; ++j) {
            oacc0[j] = fmaf(w, (float)af0[j], oacc0[j]);
            oacc1[j] = fmaf(w, (float)af1[j], oacc1[j]);
        }

        // advance (r,c) -> next pair (branchless, R8-verified)
        ++pc;
        const int wrap = (pc >= 32) ? 1 : 0;
        pr += wrap;
        pc = wrap ? (pr + 1) : pc;
    }

    // ---- cross-nlane reduce (pairs partitioned by nlane) ----
    #pragma unroll
    for (int off = 1; off < 16; off <<= 1) {
        sw += __shfl_xor(sw, off);
        #pragma unroll
        for (int j = 0; j < 8; ++j) {
            oacc0[j] += __shfl_xor(oacc0[j], off);
            oacc1[j] += __shfl_xor(oacc1[j], off);
        }
    }
    const float inv = 1.0f / sw;

    if (nlane == 0) {                                    // lanes g*16: e-slice g
        float* __restrict__ ob = out + (size_t)b * NE;
        f32x4 q;
        q = (f32x4){oacc0[0]*inv, oacc0[1]*inv, oacc0[2]*inv, oacc0[3]*inv};
        *(f32x4*)&ob[8*g + 0] = q;
        q = (f32x4){oacc0[4]*inv, oacc0[5]*inv, oacc0[6]*inv, oacc0[7]*inv};
        *(f32x4*)&ob[8*g + 4] = q;
        q = (f32x4){oacc1[0]*inv, oacc1[1]*inv, oacc1[2]*inv, oacc1[3]*inv};
        *(f32x4*)&ob[32 + 8*g + 0] = q;
        q = (f32x4){oacc1[4]*inv, oacc1[5]*inv, oacc1[6]*inv, oacc1[7]*inv};
        *(f32x4*)&ob[32 + 8*g + 4] = q;
    }

    // ---- attn = raw w * inv (same-wave LDS read-back, coalesced stores) ----
    float* __restrict__ attn_b = attn + (size_t)b * NP;
    #pragma unroll
    for (int k = 0; k < 8; ++k) {
        const int p = (k << 6) + lane;
        if (p < NP) attn_b[p] = s_w[wv][p] * inv;
    }
}

extern "C" void kernel_launch(void* const* d_in, const int* in_sizes, int n_in,
                              void* d_out, int out_size, void* d_ws, size_t ws_size,
                              hipStream_t stream) {
    const float* x  = (const float*)d_in[0];
    const float* W1 = (const float*)d_in[1];
    const float* b1 = (const float*)d_in[2];
    const float* w2 = (const float*)d_in[3];
    const float* b2 = (const float*)d_in[4];

    const int B = in_sizes[0] / (NF * NE);             // 2048
    float* out_p  = (float*)d_out;                     // (B,1,64) flat
    float* attn_p = (float*)d_out + (size_t)B * NE;    // (B,496,1) flat

    afm_fwd<<<(B + 3) / 4, 256, 0, stream>>>(x, W1, b1, w2, b2, out_p, attn_p, B);
}